// Round 2
// baseline (961.007 us; speedup 1.0000x reference)
//
#include <hip/hip_runtime.h>
#include <math.h>

#define BATCH  2
#define S_LEN  2048
#define DMODEL 1024
#define NH     16
#define DHEAD  64

// ---------------------------------------------------------------------------
// Kernel 1: projection  out[m][n] = sum_d Q[m][d]*W[n][d] + bias[n]
// scattered to [b][h][s][dk] layout. Tile 64x64, 256 thr, 4x4/thread, KB=16.
// ---------------------------------------------------------------------------
__global__ __launch_bounds__(256) void qkv_proj(
    const float* __restrict__ Q, const float* __restrict__ W,
    const float* __restrict__ bias, float* __restrict__ out)
{
    __shared__ float As[16][68];   // k-major: As[k][m]
    __shared__ float Ws[16][68];   // k-major: Ws[k][n]

    const int tid = threadIdx.x;
    const int tx  = tid & 15;      // n sub-block
    const int ty  = tid >> 4;      // m sub-block
    const int m0  = blockIdx.y * 64;
    const int n0  = blockIdx.x * 64;

    const int lrow = tid >> 2;         // 0..63
    const int lk4  = (tid & 3) * 4;    // 0,4,8,12

    float acc[4][4] = {};

    for (int k0 = 0; k0 < DMODEL; k0 += 16) {
        float4 a4 = *(const float4*)(Q + (size_t)(m0 + lrow) * DMODEL + k0 + lk4);
        float4 w4 = *(const float4*)(W + (size_t)(n0 + lrow) * DMODEL + k0 + lk4);
        __syncthreads();   // previous iteration's readers done
        As[lk4+0][lrow] = a4.x; As[lk4+1][lrow] = a4.y;
        As[lk4+2][lrow] = a4.z; As[lk4+3][lrow] = a4.w;
        Ws[lk4+0][lrow] = w4.x; Ws[lk4+1][lrow] = w4.y;
        Ws[lk4+2][lrow] = w4.z; Ws[lk4+3][lrow] = w4.w;
        __syncthreads();
        #pragma unroll
        for (int kk = 0; kk < 16; ++kk) {
            float4 av = *(const float4*)&As[kk][ty*4];
            float4 bv = *(const float4*)&Ws[kk][tx*4];
            float a[4] = {av.x, av.y, av.z, av.w};
            float b[4] = {bv.x, bv.y, bv.z, bv.w};
            #pragma unroll
            for (int i = 0; i < 4; ++i)
                #pragma unroll
                for (int j = 0; j < 4; ++j)
                    acc[i][j] += a[i] * b[j];
        }
    }

    // epilogue: n-tile is 64-wide & aligned -> exactly one head per block
    const int h  = n0 >> 6;
    const float4 bb = *(const float4*)(bias + n0 + tx*4);
    #pragma unroll
    for (int i = 0; i < 4; ++i) {
        int m = m0 + ty*4 + i;
        int b = m >> 11;           // /2048
        int s = m & 2047;
        float4 o;
        o.x = acc[i][0] + bb.x; o.y = acc[i][1] + bb.y;
        o.z = acc[i][2] + bb.z; o.w = acc[i][3] + bb.w;
        *(float4*)(out + (((size_t)b*NH + h)*S_LEN + s)*DHEAD + tx*4) = o;
    }
}

// ---------------------------------------------------------------------------
// Kernel 2: flash-style exp-attention. Block = (b, h, 64-query tile).
// Raw exp (no max subtraction) => plain running sums, no rescale needed.
// Q,K kept d-major in LDS so the score phase reads both operands as b128.
// Staging: tile = 64x64 floats = 1024 float4s; thread t copies float4s
// t, t+256, t+512, t+768 (row = f>>4, col = (f&15)*4) — full tile, coalesced.
// ---------------------------------------------------------------------------
__global__ __launch_bounds__(256) void attn(
    const float* __restrict__ qbuf, const float* __restrict__ kbuf,
    const float* __restrict__ vbuf, const float* __restrict__ mask,
    float* __restrict__ out)
{
    __shared__ float Qts[64][68];   // [d][query]
    __shared__ float Kts[64][68];   // [d][key]
    __shared__ float Vt [64][68];   // [key][dv]
    __shared__ float Sc [64][68];   // [query][key]
    __shared__ float mk[64];
    __shared__ float rsred[64][17];
    __shared__ float rsum[64];

    const int tid = threadIdx.x;
    const int tx  = tid & 15;
    const int ty  = tid >> 4;
    const int q0  = blockIdx.x * 64;
    const int h   = blockIdx.y;
    const int b   = blockIdx.z;

    const float* qb = qbuf + ((size_t)b*NH + h)*S_LEN*DHEAD;
    const float* kb = kbuf + ((size_t)b*NH + h)*S_LEN*DHEAD;
    const float* vb = vbuf + ((size_t)b*NH + h)*S_LEN*DHEAD;

    // stage Q tile (full 64x64), transposed to d-major
    #pragma unroll
    for (int r = 0; r < 4; ++r) {
        int f   = tid + r*256;      // float4 index in 64x16 grid
        int row = f >> 4;           // query 0..63
        int c   = (f & 15) * 4;     // d 0..60
        float4 q4 = *(const float4*)(qb + (size_t)(q0 + row)*DHEAD + c);
        Qts[c+0][row] = q4.x; Qts[c+1][row] = q4.y;
        Qts[c+2][row] = q4.z; Qts[c+3][row] = q4.w;
    }

    float acc[4][4] = {};
    float rs[4] = {};
    const float scale = 0.125f;   // 1/sqrt(64)

    for (int k0 = 0; k0 < S_LEN; k0 += 64) {
        float4 kv4[4], vv4[4];
        #pragma unroll
        for (int r = 0; r < 4; ++r) {
            int f   = tid + r*256;
            int row = f >> 4;
            int c   = (f & 15) * 4;
            kv4[r] = *(const float4*)(kb + (size_t)(k0 + row)*DHEAD + c);
            vv4[r] = *(const float4*)(vb + (size_t)(k0 + row)*DHEAD + c);
        }
        __syncthreads();   // prev PV readers done (also covers Qts on iter 0)
        #pragma unroll
        for (int r = 0; r < 4; ++r) {
            int f   = tid + r*256;
            int row = f >> 4;
            int c   = (f & 15) * 4;
            Kts[c+0][row] = kv4[r].x; Kts[c+1][row] = kv4[r].y;
            Kts[c+2][row] = kv4[r].z; Kts[c+3][row] = kv4[r].w;
            *(float4*)&Vt[row][c] = vv4[r];
        }
        if (tid < 64) mk[tid] = mask[(size_t)b*S_LEN + k0 + tid];
        __syncthreads();

        // scores: 4 queries (ty*4+i) x 4 keys (tx*4+j) per thread
        float d[4][4] = {};
        #pragma unroll 8
        for (int dd = 0; dd < 64; ++dd) {
            float4 qv = *(const float4*)&Qts[dd][ty*4];
            float4 kv = *(const float4*)&Kts[dd][tx*4];
            float qa[4] = {qv.x, qv.y, qv.z, qv.w};
            float ka[4] = {kv.x, kv.y, kv.z, kv.w};
            #pragma unroll
            for (int i = 0; i < 4; ++i)
                #pragma unroll
                for (int j = 0; j < 4; ++j)
                    d[i][j] += qa[i] * ka[j];
        }
        #pragma unroll
        for (int i = 0; i < 4; ++i) {
            float4 e4;
            e4.x = __expf(d[i][0]*scale) * mk[tx*4+0];
            e4.y = __expf(d[i][1]*scale) * mk[tx*4+1];
            e4.z = __expf(d[i][2]*scale) * mk[tx*4+2];
            e4.w = __expf(d[i][3]*scale) * mk[tx*4+3];
            rs[i] += e4.x + e4.y + e4.z + e4.w;
            *(float4*)&Sc[ty*4+i][tx*4] = e4;
        }
        __syncthreads();

        // PV: acc[i][*] += Sc[q][j] * V[j][dv],  dv block = tx*4..+4
        for (int j0 = 0; j0 < 64; j0 += 4) {
            float sv[4][4];
            #pragma unroll
            for (int i = 0; i < 4; ++i) {
                float4 t = *(const float4*)&Sc[ty*4+i][j0];
                sv[i][0]=t.x; sv[i][1]=t.y; sv[i][2]=t.z; sv[i][3]=t.w;
            }
            #pragma unroll
            for (int jj = 0; jj < 4; ++jj) {
                float4 vv = *(const float4*)&Vt[j0+jj][tx*4];
                #pragma unroll
                for (int i = 0; i < 4; ++i) {
                    float s = sv[i][jj];
                    acc[i][0] += s*vv.x; acc[i][1] += s*vv.y;
                    acc[i][2] += s*vv.z; acc[i][3] += s*vv.w;
                }
            }
        }
    }

    // reduce row sums across the 16 tx lanes
    #pragma unroll
    for (int i = 0; i < 4; ++i) rsred[ty*4+i][tx] = rs[i];
    __syncthreads();
    if (tid < 64) {
        float s = 0.f;
        #pragma unroll
        for (int j = 0; j < 16; ++j) s += rsred[tid][j];
        rsum[tid] = s + 1e-8f;
    }
    __syncthreads();

    #pragma unroll
    for (int i = 0; i < 4; ++i) {
        int qi = ty*4 + i;
        float inv = 1.0f / rsum[qi];
        float4 o;
        o.x = acc[i][0]*inv; o.y = acc[i][1]*inv;
        o.z = acc[i][2]*inv; o.w = acc[i][3]*inv;
        *(float4*)(out + ((size_t)b*S_LEN + q0 + qi)*DMODEL + h*DHEAD + tx*4) = o;
    }
}

// ---------------------------------------------------------------------------
extern "C" void kernel_launch(void* const* d_in, const int* in_sizes, int n_in,
                              void* d_out, int out_size, void* d_ws, size_t ws_size,
                              hipStream_t stream) {
    const float* Q    = (const float*)d_in[0];
    const float* msk  = (const float*)d_in[1];
    const float* W_Q  = (const float*)d_in[2];
    const float* b_Q  = (const float*)d_in[3];
    const float* W_K  = (const float*)d_in[4];
    const float* b_K  = (const float*)d_in[5];
    const float* W_V  = (const float*)d_in[6];
    const float* b_V  = (const float*)d_in[7];
    float* out = (float*)d_out;

    const size_t per = (size_t)BATCH * NH * S_LEN * DHEAD;   // 4,194,304 floats
    float* qw = (float*)d_ws;        // needs 3*per*4 = 48 MB of workspace
    float* kw = qw + per;
    float* vw = kw + per;

    dim3 blk(256);
    dim3 gProj(DMODEL/64, (BATCH*S_LEN)/64);                 // 16 x 64
    qkv_proj<<<gProj, blk, 0, stream>>>(Q, W_Q, b_Q, qw);
    qkv_proj<<<gProj, blk, 0, stream>>>(Q, W_K, b_K, kw);
    qkv_proj<<<gProj, blk, 0, stream>>>(Q, W_V, b_V, vw);

    dim3 gAttn(S_LEN/64, NH, BATCH);                         // 32 x 16 x 2
    attn<<<gAttn, blk, 0, stream>>>(qw, kw, vw, msk, out);
}

// Round 3
// 374.892 us; speedup vs baseline: 2.5634x; 2.5634x over previous
//
#include <hip/hip_runtime.h>
#include <math.h>

#define BATCH  2
#define S_LEN  2048
#define DMODEL 1024
#define NH     16
#define DHEAD  64

typedef __attribute__((ext_vector_type(8))) short bf16x8;   // 8 bf16 = 4 VGPRs
typedef __attribute__((ext_vector_type(4))) float f32x4;

#define MFMA16(a,b,c) __builtin_amdgcn_mfma_f32_16x16x32_bf16((a),(b),(c),0,0,0)

__device__ __forceinline__ unsigned short f2bf(float x) {
    union { float f; unsigned int u; } v; v.f = x;
    unsigned int r = v.u + 0x7fffu + ((v.u >> 16) & 1u);   // RNE
    return (unsigned short)(r >> 16);
}
__device__ __forceinline__ float bf2f(unsigned short x) {
    union { float f; unsigned int u; } v; v.u = ((unsigned int)x) << 16;
    return v.f;
}
__device__ __forceinline__ unsigned int pk2(float a, float b) {
    return (unsigned int)f2bf(a) | ((unsigned int)f2bf(b) << 16);
}
__device__ __forceinline__ void gl2lds16(const void* g, void* l) {
    __builtin_amdgcn_global_load_lds(
        (const __attribute__((address_space(1))) void*)(g),
        (__attribute__((address_space(3))) void*)(l), 16, 0, 0);
}

// ---------------------------------------------------------------------------
// fp32 -> bf16 bulk convert, 8 elems/thread
// ---------------------------------------------------------------------------
__global__ __launch_bounds__(256) void cvt_bf16(
    const float* __restrict__ src, unsigned short* __restrict__ dst, int n8)
{
    int i = blockIdx.x * blockDim.x + threadIdx.x;
    if (i >= n8) return;
    float4 a = ((const float4*)src)[2*i];
    float4 b = ((const float4*)src)[2*i + 1];
    uint4 o;
    o.x = pk2(a.x, a.y); o.y = pk2(a.z, a.w);
    o.z = pk2(b.x, b.y); o.w = pk2(b.z, b.w);
    ((uint4*)dst)[i] = o;
}

// ---------------------------------------------------------------------------
// Projection GEMM: C[m=(b,s)][n] = sum_d Qbf[m][d] * W[n][d] + bias[n]
// 128x128 tile, BK=32, 256 thr = 4 waves (2x2 of 64x64), 16 MFMA/wave/iter.
// z = 0/1 -> qw/kw [b,h,s,dk] (operands swapped so regs pack along dk)
// z = 2   -> vt    [b,h,dv,s] (unswapped so regs pack along s)
// ---------------------------------------------------------------------------
__global__ __launch_bounds__(256) void proj_mfma(
    const unsigned short* __restrict__ Abf,   // [4096][1024]
    const unsigned short* __restrict__ Wbf,   // [3][1024][1024]
    const float* __restrict__ bQ, const float* __restrict__ bK,
    const float* __restrict__ bV,
    unsigned short* __restrict__ qw, unsigned short* __restrict__ kw,
    unsigned short* __restrict__ vt)
{
    __shared__ __align__(16) unsigned short At[128*32];
    __shared__ __align__(16) unsigned short Bt[128*32];

    const int tid  = threadIdx.x;
    const int lane = tid & 63;
    const int wv   = tid >> 6;
    const int wm   = (wv >> 1) * 64;
    const int wn   = (wv & 1) * 64;
    const int q15  = lane & 15;
    const int quad = lane >> 4;
    const int z    = blockIdx.z;
    const int n0   = blockIdx.x * 128;
    const int m0   = blockIdx.y * 128;

    const unsigned short* Wz = Wbf + (size_t)z * DMODEL * DMODEL;
    const float* bias = (z == 0) ? bQ : ((z == 1) ? bK : bV);

    f32x4 zero4 = {0.f, 0.f, 0.f, 0.f};
    f32x4 acc[4][4];
    #pragma unroll
    for (int i = 0; i < 4; ++i)
        #pragma unroll
        for (int j = 0; j < 4; ++j) acc[i][j] = zero4;

    for (int k0 = 0; k0 < DMODEL; k0 += 32) {
        __syncthreads();   // previous readers done
        #pragma unroll
        for (int c = 0; c < 2; ++c) {
            int o   = tid * 16 + c * 4096;      // byte offset in 8KB tile
            int row = o >> 6;                   // 64B per row (32 bf16)
            int cb  = o & 63;
            gl2lds16(Abf + (size_t)(m0 + row) * DMODEL + k0 + (cb >> 1),
                     (char*)At + o);
            gl2lds16(Wz  + (size_t)(n0 + row) * DMODEL + k0 + (cb >> 1),
                     (char*)Bt + o);
        }
        __syncthreads();   // vmcnt(0) drained by barrier

        bf16x8 af[4], bf[4];
        #pragma unroll
        for (int i = 0; i < 4; ++i)
            af[i] = *(const bf16x8*)(At + (wm + i*16 + q15) * 32 + quad * 8);
        #pragma unroll
        for (int j = 0; j < 4; ++j)
            bf[j] = *(const bf16x8*)(Bt + (wn + j*16 + q15) * 32 + quad * 8);

        if (z < 2) {
            #pragma unroll
            for (int i = 0; i < 4; ++i)
                #pragma unroll
                for (int j = 0; j < 4; ++j)
                    acc[i][j] = MFMA16(bf[j], af[i], acc[i][j]);
        } else {
            #pragma unroll
            for (int i = 0; i < 4; ++i)
                #pragma unroll
                for (int j = 0; j < 4; ++j)
                    acc[i][j] = MFMA16(af[i], bf[j], acc[i][j]);
        }
    }

    if (z < 2) {
        unsigned short* outp = (z == 0) ? qw : kw;
        // D[row=quad*4+r = n-local][col=lane&15 = m-local]
        #pragma unroll
        for (int i = 0; i < 4; ++i) {
            int mg = m0 + wm + i*16 + q15;
            int b2 = mg >> 11, s = mg & 2047;
            #pragma unroll
            for (int j = 0; j < 4; ++j) {
                int nbase = n0 + wn + j*16 + quad*4;    // + r
                int h = nbase >> 6, dk = nbase & 63;
                float4 bv4 = *(const float4*)(bias + nbase);
                f32x4 v = acc[i][j];
                uint2 u;
                u.x = pk2(v.x + bv4.x, v.y + bv4.y);
                u.y = pk2(v.z + bv4.z, v.w + bv4.w);
                *(uint2*)(outp + (((size_t)b2*NH + h)*S_LEN + s)*DHEAD + dk) = u;
            }
        }
    } else {
        // D[row=quad*4+r = m-local(s)][col=lane&15 = n-local(dv)]
        #pragma unroll
        for (int i = 0; i < 4; ++i) {
            int sbase = m0 + wm + i*16 + quad*4;        // + r
            int b2 = sbase >> 11, s0 = sbase & 2047;
            #pragma unroll
            for (int j = 0; j < 4; ++j) {
                int ng = n0 + wn + j*16 + q15;
                int h = ng >> 6, dv = ng & 63;
                float bvv = bias[ng];
                f32x4 v = acc[i][j];
                uint2 u;
                u.x = pk2(v.x + bvv, v.y + bvv);
                u.y = pk2(v.z + bvv, v.w + bvv);
                *(uint2*)(vt + (((size_t)b2*NH + h)*DHEAD + dv)*S_LEN + s0) = u;
            }
        }
    }
}

// ---------------------------------------------------------------------------
// Attention: block = (64-q tile, h, b), 4 waves x 16 q-rows.
// K/V fragments straight from global (L1/L2); P via per-wave LDS round-trip.
// ---------------------------------------------------------------------------
__global__ __launch_bounds__(256) void attn_mfma(
    const unsigned short* __restrict__ qw, const unsigned short* __restrict__ kw,
    const unsigned short* __restrict__ vt, const float* __restrict__ mask,
    float* __restrict__ out)
{
    __shared__ __align__(16) unsigned short P[4][16][72];  // per-wave, 144B rows

    const int tid  = threadIdx.x;
    const int lane = tid & 63;
    const int wv   = tid >> 6;
    const int q15  = lane & 15;
    const int quad = lane >> 4;
    const int q0   = blockIdx.x * 64;
    const int h    = blockIdx.y;
    const int b    = blockIdx.z;

    const size_t headoff = ((size_t)b * NH + h) * S_LEN * DHEAD;
    const unsigned short* qb = qw + headoff;
    const unsigned short* kb = kw + headoff;
    const unsigned short* vb = vt + headoff;        // [dv][s]
    const float* mkp = mask + (size_t)b * S_LEN;

    // Q fragments: fixed for whole kernel. A[m=q at lane&15][k=d at quad*8+j]
    bf16x8 qf0 = *(const bf16x8*)(qb + (size_t)(q0 + wv*16 + q15)*DHEAD + quad*8);
    bf16x8 qf1 = *(const bf16x8*)(qb + (size_t)(q0 + wv*16 + q15)*DHEAD + 32 + quad*8);

    f32x4 zero4 = {0.f, 0.f, 0.f, 0.f};
    f32x4 oacc[4];
    #pragma unroll
    for (int j = 0; j < 4; ++j) oacc[j] = zero4;
    float rs[4] = {0.f, 0.f, 0.f, 0.f};
    const float scale = 0.125f;   // 1/sqrt(64)

    for (int k0 = 0; k0 < S_LEN; k0 += 64) {
        // ---- QK^T: 4 key-subtiles of 16, K=64 via two chained MFMAs ----
        #pragma unroll
        for (int ks = 0; ks < 4; ++ks) {
            const unsigned short* kr = kb + (size_t)(k0 + ks*16 + q15)*DHEAD;
            bf16x8 kf0 = *(const bf16x8*)(kr + quad*8);
            bf16x8 kf1 = *(const bf16x8*)(kr + 32 + quad*8);
            f32x4 s4 = zero4;
            s4 = MFMA16(qf0, kf0, s4);
            s4 = MFMA16(qf1, kf1, s4);
            float mkv = mkp[k0 + ks*16 + q15];
            #pragma unroll
            for (int r = 0; r < 4; ++r) {
                unsigned short pb = f2bf(__expf(s4[r] * scale) * mkv);
                rs[r] += bf2f(pb);   // denominator matches bf16 numerator
                P[wv][quad*4 + r][ks*16 + q15] = pb;
            }
        }
        __syncthreads();
        // ---- PV: P (16x64) @ V (64x64), V^T rows straight from global ----
        bf16x8 pf0 = *(const bf16x8*)(&P[wv][q15][quad*8]);
        bf16x8 pf1 = *(const bf16x8*)(&P[wv][q15][32 + quad*8]);
        #pragma unroll
        for (int nj = 0; nj < 4; ++nj) {
            const unsigned short* vr = vb + (size_t)(nj*16 + q15)*S_LEN + k0;
            bf16x8 vf0 = *(const bf16x8*)(vr + quad*8);
            bf16x8 vf1 = *(const bf16x8*)(vr + 32 + quad*8);
            oacc[nj] = MFMA16(pf0, vf0, oacc[nj]);
            oacc[nj] = MFMA16(pf1, vf1, oacc[nj]);
        }
        __syncthreads();   // P readers done before next tile's writes
    }

    // row sums: reduce over the 16 key-lanes (masks 1,2,4,8 stay in-group)
    #pragma unroll
    for (int r = 0; r < 4; ++r) {
        float v = rs[r];
        v += __shfl_xor(v, 1); v += __shfl_xor(v, 2);
        v += __shfl_xor(v, 4); v += __shfl_xor(v, 8);
        rs[r] = 1.0f / (v + 1e-8f);
    }

    // out[b][s][h*64+dv]; s = q0+wv*16+quad*4+r, dv = nj*16+q15
    #pragma unroll
    for (int r = 0; r < 4; ++r) {
        size_t row = ((size_t)b*S_LEN + q0 + wv*16 + quad*4 + r)*DMODEL + h*DHEAD;
        #pragma unroll
        for (int nj = 0; nj < 4; ++nj)
            out[row + nj*16 + q15] = oacc[nj][r] * rs[r];
    }
}

// ---------------------------------------------------------------------------
extern "C" void kernel_launch(void* const* d_in, const int* in_sizes, int n_in,
                              void* d_out, int out_size, void* d_ws, size_t ws_size,
                              hipStream_t stream) {
    const float* Q    = (const float*)d_in[0];
    const float* msk  = (const float*)d_in[1];
    const float* W_Q  = (const float*)d_in[2];
    const float* b_Q  = (const float*)d_in[3];
    const float* W_K  = (const float*)d_in[4];
    const float* b_K  = (const float*)d_in[5];
    const float* W_V  = (const float*)d_in[6];
    const float* b_V  = (const float*)d_in[7];
    float* out = (float*)d_out;

    unsigned short* wsu = (unsigned short*)d_ws;
    unsigned short* Qbf = wsu;                                   // 4M
    unsigned short* Wbf = Qbf + (size_t)4096*1024;               // 3M
    unsigned short* qwb = Wbf + (size_t)3*1024*1024;             // 4M
    unsigned short* kwb = qwb + (size_t)4*1024*1024;             // 4M
    unsigned short* vtb = kwb + (size_t)4*1024*1024;             // 4M  (38MB total)

    cvt_bf16<<<2048, 256, 0, stream>>>(Q,   Qbf,                4096*1024/8);
    cvt_bf16<<<512,  256, 0, stream>>>(W_Q, Wbf,                1024*1024/8);
    cvt_bf16<<<512,  256, 0, stream>>>(W_K, Wbf + 1024*1024,    1024*1024/8);
    cvt_bf16<<<512,  256, 0, stream>>>(W_V, Wbf + 2*1024*1024,  1024*1024/8);

    proj_mfma<<<dim3(8, 32, 3), 256, 0, stream>>>(
        Qbf, Wbf, b_Q, b_K, b_V, qwb, kwb, vtb);

    attn_mfma<<<dim3(S_LEN/64, NH, BATCH), 256, 0, stream>>>(
        qwb, kwb, vtb, msk, out);
}